// Round 3
// baseline (228.488 us; speedup 1.0000x reference)
//
#include <hip/hip_runtime.h>
#include <math.h>

#define BLOCK 64   // one wave per block; 64x64 upper-triangle tiles

// Scale all coords by log2(e): then exp2(|dt'-dp'|) == e^{|dt-dp|}, and the
// cutoff test runs on squared scaled distances (no sqrt dependency).
#define L2E 1.4426950408889634f

// den(e) = prod_k (1 + C_k e), num(e) = sum_k prod_{l!=k} (1 + C_l e)
// with C_k = e^{-0.5}, e^{-1}, e^{-2}, e^{-4}. Then sum_k sigmoid(a_k - d)
// = num(e)/den(e) with e = exp(d). Elementary-symmetric coefficients:
#define A1 1.1280610230094226f
#define A2 0.3753279228541867f
#define A3 0.0366994760193147f
#define A4 0.0005530843701478f
#define B1 3.3841830690282678f   // 3*A1
#define B2 0.7506558457083734f   // 2*A2
#define B3 0.0366994760193147f   // A3

__global__ __launch_bounds__(BLOCK) void lddt_pairs(
    const float* __restrict__ pred, const float* __restrict__ truec,
    const int* __restrict__ isdna, const int* __restrict__ isrna,
    float* __restrict__ ws, int N, int C)
{
  // linear tile id -> upper-triangle (ic, jc), jc >= ic
  const int t = blockIdx.x;
  const int b = blockIdx.y;
  const float fC = (float)C;
  int ic = (int)((2.0f*fC + 1.0f -
                  sqrtf((2.0f*fC + 1.0f)*(2.0f*fC + 1.0f) - 8.0f*(float)t)) * 0.5f);
  if (ic > C - 1) ic = C - 1;
  if (ic < 0) ic = 0;
  while (ic > 0 && t < ic*C - ((ic*(ic-1)) >> 1)) --ic;
  while (t >= (ic+1)*C - (((ic+1)*ic) >> 1)) ++ic;
  const int jc = ic + t - (ic*C - ((ic*(ic-1)) >> 1));
  const bool diag = (ic == jc);

  const float C30SQ = (30.0f*L2E)*(30.0f*L2E);
  const float C15SQ = (15.0f*L2E)*(15.0f*L2E);

  __shared__ float4 sp[BLOCK];  // scaled pred xyz ; w = cutoff^2 if j is nucleic else 15-cutoff^2
  __shared__ float4 st[BLOCK];  // scaled true xyz

  const int tid = threadIdx.x;
  {
    const int j = jc * BLOCK + tid;
    const size_t base = (size_t)b * N + j;
    const float* pp = pred  + base * 3;
    const float* tt = truec + base * 3;
    const float cutj2 = ((isdna[base] | isrna[base]) != 0) ? C30SQ : C15SQ;
    sp[tid] = make_float4(pp[0]*L2E, pp[1]*L2E, pp[2]*L2E, cutj2);
    st[tid] = make_float4(tt[0]*L2E, tt[1]*L2E, tt[2]*L2E, 0.0f);
  }

  const int i = ic * BLOCK + tid;
  const size_t ibase = (size_t)b * N + i;
  const float pix = pred[ibase*3+0]*L2E, piy = pred[ibase*3+1]*L2E, piz = pred[ibase*3+2]*L2E;
  const float tix = truec[ibase*3+0]*L2E, tiy = truec[ibase*3+1]*L2E, tiz = truec[ibase*3+2]*L2E;
  const bool nuci = ((isdna[ibase] | isrna[ibase]) != 0);

  __syncthreads();

  float sum = 0.0f;
  int   cnt = 0;

  if (!diag) {
#pragma unroll 8
    for (int jj = 0; jj < BLOCK; ++jj) {
      const float4 P  = sp[jj];
      const float4 T4 = st[jj];
      float dx = P.x - pix, dy = P.y - piy, dz = P.z - piz;
      float dp = __builtin_amdgcn_sqrtf(fmaf(dx, dx, fmaf(dy, dy, dz * dz)));
      float ex = T4.x - tix, ey = T4.y - tiy, ez = T4.z - tiz;
      float d2t = fmaf(ex, ex, fmaf(ey, ey, ez * ez));
      float dt = __builtin_amdgcn_sqrtf(d2t);

      float e = __builtin_amdgcn_exp2f(fabsf(dt - dp));
      float den = fmaf(fmaf(fmaf(fmaf(A4, e, A3), e, A2), e, A1), e, 1.0f);
      float num = fmaf(fmaf(fmaf(B3, e, B2), e, B1), e, 4.0f);
      float eps4 = num * __builtin_amdgcn_rcpf(den);

      float cut2 = nuci ? P.w : C15SQ;
      bool inc = (d2t < cut2);
      cnt += (int)__popcll(__ballot(inc));
      sum += inc ? eps4 : 0.0f;
    }
  } else {
#pragma unroll 8
    for (int jj = 0; jj < BLOCK; ++jj) {
      const float4 P  = sp[jj];
      const float4 T4 = st[jj];
      float dx = P.x - pix, dy = P.y - piy, dz = P.z - piz;
      float dp = __builtin_amdgcn_sqrtf(fmaf(dx, dx, fmaf(dy, dy, dz * dz)));
      float ex = T4.x - tix, ey = T4.y - tiy, ez = T4.z - tiz;
      float d2t = fmaf(ex, ex, fmaf(ey, ey, ez * ez));
      float dt = __builtin_amdgcn_sqrtf(d2t);

      float e = __builtin_amdgcn_exp2f(fabsf(dt - dp));
      float den = fmaf(fmaf(fmaf(fmaf(A4, e, A3), e, A2), e, A1), e, 1.0f);
      float num = fmaf(fmaf(fmaf(B3, e, B2), e, B1), e, 4.0f);
      float eps4 = num * __builtin_amdgcn_rcpf(den);

      float cut2 = nuci ? P.w : C15SQ;
      bool inc = (d2t < cut2) && (jj != tid);
      cnt += (int)__popcll(__ballot(inc));
      sum += inc ? eps4 : 0.0f;
    }
  }

  // wave64 butterfly reduce on sum (cnt already wave-uniform via ballot)
  for (int off = 32; off > 0; off >>= 1)
    sum += __shfl_down(sum, off, 64);

  if (tid == 0) {
    const float w = diag ? 1.0f : 2.0f;
    // ws layout: [0..1] eps sums, [2..3] counts, [4] ticket (uint)
    atomicAdd(&ws[b],     0.25f * w * sum);
    atomicAdd(&ws[2 + b], w * (float)cnt);
    __threadfence();
    unsigned* ticket = (unsigned*)(ws + 4);
    unsigned total = gridDim.x * gridDim.y;
    unsigned old = atomicAdd(ticket, 1u);
    if (old == total - 1u) {
      // last block: all contributions are in (atomic order + fences).
      // atomicAdd(p, 0.0f) = device-coherent read bypassing L1.
      float s0 = atomicAdd(&ws[0], 0.0f);
      float s1 = atomicAdd(&ws[1], 0.0f);
      float c0 = atomicAdd(&ws[2], 0.0f);
      float c1 = atomicAdd(&ws[3], 0.0f);
      float lddt = 0.5f * (s0 / fmaxf(c0, 1.0f) + s1 / fmaxf(c1, 1.0f));
      float* out = (float*)(((unsigned long long*)(ws + 8))[0]);
      out[0] = 1.0f - lddt;
    }
  }
}

// tiny helper: stash the out pointer in ws so the ticket winner can store it
__global__ void lddt_setptr(float* ws, float* out)
{
  if (threadIdx.x == 0) {
    ((unsigned long long*)(ws + 8))[0] = (unsigned long long)out;
    // zero accumulators + ticket
    ws[0] = 0.0f; ws[1] = 0.0f; ws[2] = 0.0f; ws[3] = 0.0f;
    ((unsigned*)(ws + 4))[0] = 0u;
  }
}

extern "C" void kernel_launch(void* const* d_in, const int* in_sizes, int n_in,
                              void* d_out, int out_size, void* d_ws, size_t ws_size,
                              hipStream_t stream)
{
  const float* pred  = (const float*)d_in[0];
  const float* truec = (const float*)d_in[1];
  const int*   isdna = (const int*)d_in[2];
  const int*   isrna = (const int*)d_in[3];
  float* out = (float*)d_out;
  float* ws  = (float*)d_ws;

  const int B = 2;
  const int N = in_sizes[2] / B;       // 4096
  const int C = N / BLOCK;             // 64 chunks
  const int T = C * (C + 1) / 2;       // 2080 triangle tiles

  // init accumulators/ticket + stash out ptr (single tiny kernel, no memset dispatch)
  lddt_setptr<<<1, 64, 0, stream>>>(ws, out);

  dim3 grid(T, B);
  lddt_pairs<<<grid, BLOCK, 0, stream>>>(pred, truec, isdna, isrna, ws, N, C);
}

// Round 4
// 81.577 us; speedup vs baseline: 2.8009x; 2.8009x over previous
//
#include <hip/hip_runtime.h>
#include <math.h>

#define BLOCK 64   // one wave per block; 64x64 upper-triangle tiles

// Coords pre-scaled by log2(e): exp2(|dt'-dp'|) == e^{|dt-dp|}; cutoff test
// runs on squared scaled distances (no sqrt->cmp dependency).
#define L2E 1.4426950408889634f

// sum_k sigmoid(a_k - d) = num(e)/den(e), e = exp(d), a_k = .5,1,2,4.
// den(e) = prod_k (1 + C_k e), num(e) = d/de-style cofactor sum; coefficients
// are elementary symmetric functions of C_k = e^{-a_k}.
#define A1 1.1280610230094226f
#define A2 0.3753279228541867f
#define A3 0.0366994760193147f
#define A4 0.0005530843701478f
#define B1 3.3841830690282678f   // 3*A1
#define B2 0.7506558457083734f   // 2*A2
#define B3 0.0366994760193147f   // A3

__global__ __launch_bounds__(BLOCK) void lddt_pairs(
    const float* __restrict__ pred, const float* __restrict__ truec,
    const int* __restrict__ isdna, const int* __restrict__ isrna,
    float2* __restrict__ part, int N, int C, int T)
{
  // linear tile id -> upper-triangle (ic, jc), jc >= ic (uniform scalar math)
  const int t = blockIdx.x;
  const int b = blockIdx.y;
  const float fC = (float)C;
  int ic = (int)((2.0f*fC + 1.0f -
                  sqrtf((2.0f*fC + 1.0f)*(2.0f*fC + 1.0f) - 8.0f*(float)t)) * 0.5f);
  if (ic > C - 1) ic = C - 1;
  if (ic < 0) ic = 0;
  while (ic > 0 && t < ic*C - ((ic*(ic-1)) >> 1)) --ic;
  while (t >= (ic+1)*C - (((ic+1)*ic) >> 1)) ++ic;
  const int jc = ic + t - (ic*C - ((ic*(ic-1)) >> 1));
  const bool diag = (ic == jc);

  const float C30SQ = (30.0f*L2E)*(30.0f*L2E);
  const float C15SQ = (15.0f*L2E)*(15.0f*L2E);

  __shared__ float4 sp[BLOCK];  // scaled pred xyz ; w = j's cutoff^2
  __shared__ float4 st[BLOCK];  // scaled true xyz

  const int tid = threadIdx.x;
  {
    const int j = jc * BLOCK + tid;
    const size_t base = (size_t)b * N + j;
    const float* pp = pred  + base * 3;
    const float* tt = truec + base * 3;
    const float cutj2 = ((isdna[base] | isrna[base]) != 0) ? C30SQ : C15SQ;
    sp[tid] = make_float4(pp[0]*L2E, pp[1]*L2E, pp[2]*L2E, cutj2);
    st[tid] = make_float4(tt[0]*L2E, tt[1]*L2E, tt[2]*L2E, 0.0f);
  }

  const int i = ic * BLOCK + tid;
  const size_t ibase = (size_t)b * N + i;
  const float pix = pred[ibase*3+0]*L2E, piy = pred[ibase*3+1]*L2E, piz = pred[ibase*3+2]*L2E;
  const float tix = truec[ibase*3+0]*L2E, tiy = truec[ibase*3+1]*L2E, tiz = truec[ibase*3+2]*L2E;
  const bool nuci = ((isdna[ibase] | isrna[ibase]) != 0);

  __syncthreads();

  float sum = 0.0f;
  int   cnt = 0;

  if (!diag) {
#pragma unroll 8
    for (int jj = 0; jj < BLOCK; ++jj) {
      const float4 P  = sp[jj];
      const float4 T4 = st[jj];
      float dx = P.x - pix, dy = P.y - piy, dz = P.z - piz;
      float dp = __builtin_amdgcn_sqrtf(fmaf(dx, dx, fmaf(dy, dy, dz * dz)));
      float ex = T4.x - tix, ey = T4.y - tiy, ez = T4.z - tiz;
      float d2t = fmaf(ex, ex, fmaf(ey, ey, ez * ez));
      float dt  = __builtin_amdgcn_sqrtf(d2t);

      float e = __builtin_amdgcn_exp2f(fabsf(dt - dp));
      float den = fmaf(fmaf(fmaf(fmaf(A4, e, A3), e, A2), e, A1), e, 1.0f);
      float num = fmaf(fmaf(fmaf(B3, e, B2), e, B1), e, 4.0f);
      float eps4 = num * __builtin_amdgcn_rcpf(den);

      float cut2 = nuci ? P.w : C15SQ;
      bool inc = (d2t < cut2);
      cnt += (int)__popcll(__ballot(inc));
      sum += inc ? eps4 : 0.0f;
    }
  } else {
#pragma unroll 8
    for (int jj = 0; jj < BLOCK; ++jj) {
      const float4 P  = sp[jj];
      const float4 T4 = st[jj];
      float dx = P.x - pix, dy = P.y - piy, dz = P.z - piz;
      float dp = __builtin_amdgcn_sqrtf(fmaf(dx, dx, fmaf(dy, dy, dz * dz)));
      float ex = T4.x - tix, ey = T4.y - tiy, ez = T4.z - tiz;
      float d2t = fmaf(ex, ex, fmaf(ey, ey, ez * ez));
      float dt  = __builtin_amdgcn_sqrtf(d2t);

      float e = __builtin_amdgcn_exp2f(fabsf(dt - dp));
      float den = fmaf(fmaf(fmaf(fmaf(A4, e, A3), e, A2), e, A1), e, 1.0f);
      float num = fmaf(fmaf(fmaf(B3, e, B2), e, B1), e, 4.0f);
      float eps4 = num * __builtin_amdgcn_rcpf(den);

      float cut2 = nuci ? P.w : C15SQ;
      bool inc = (d2t < cut2) && (jj != tid);
      cnt += (int)__popcll(__ballot(inc));
      sum += inc ? eps4 : 0.0f;
    }
  }

  // wave64 butterfly reduce on sum (cnt already wave-uniform via ballot)
  for (int off = 32; off > 0; off >>= 1)
    sum += __shfl_down(sum, off, 64);

  if (tid == 0) {
    const float w = diag ? 1.0f : 2.0f;
    part[(size_t)b * T + t] = make_float2(0.25f * w * sum, w * (float)cnt);
  }
}

__global__ __launch_bounds__(256) void lddt_final(
    const float2* __restrict__ part, float* __restrict__ out, int B, int T)
{
  __shared__ float rs[4], rc[4];
  float acc = 0.0f;
  for (int b = 0; b < B; ++b) {
    float s = 0.0f, c = 0.0f;
    for (int k = threadIdx.x; k < T; k += 256) {
      const float2 p = part[(size_t)b * T + k];
      s += p.x;
      c += p.y;
    }
    for (int off = 32; off > 0; off >>= 1) {
      s += __shfl_down(s, off, 64);
      c += __shfl_down(c, off, 64);
    }
    const int wave = threadIdx.x >> 6, lane = threadIdx.x & 63;
    if (lane == 0) { rs[wave] = s; rc[wave] = c; }
    __syncthreads();
    if (threadIdx.x == 0) {
      float S  = rs[0] + rs[1] + rs[2] + rs[3];
      float Cc = rc[0] + rc[1] + rc[2] + rc[3];
      acc += S / fmaxf(Cc, 1.0f);
    }
    __syncthreads();
  }
  if (threadIdx.x == 0) out[0] = 1.0f - acc / (float)B;
}

extern "C" void kernel_launch(void* const* d_in, const int* in_sizes, int n_in,
                              void* d_out, int out_size, void* d_ws, size_t ws_size,
                              hipStream_t stream)
{
  const float* pred  = (const float*)d_in[0];
  const float* truec = (const float*)d_in[1];
  const int*   isdna = (const int*)d_in[2];
  const int*   isrna = (const int*)d_in[3];
  float* out = (float*)d_out;
  float2* part = (float2*)d_ws;

  const int B = 2;
  const int N = in_sizes[2] / B;       // 4096
  const int C = N / BLOCK;             // 64 chunks
  const int T = C * (C + 1) / 2;       // 2080 triangle tiles

  dim3 grid(T, B);
  lddt_pairs<<<grid, BLOCK, 0, stream>>>(pred, truec, isdna, isrna, part, N, C, T);
  lddt_final<<<1, 256, 0, stream>>>(part, out, B, T);
}

// Round 5
// 80.112 us; speedup vs baseline: 2.8521x; 1.0183x over previous
//
#include <hip/hip_runtime.h>
#include <math.h>

#define TPB 128   // 2 waves per block; each wave owns one 64x64 triangle tile

// Coords pre-scaled by log2(e): exp2(|dt'-dp'|) == e^{|dt-dp|}; cutoff test
// runs on squared scaled distances (no sqrt->cmp dependency).
#define L2E 1.4426950408889634f

// sum_k sigmoid(a_k - d) = num(e)/den(e), e = exp(d), a_k = .5,1,2,4.
// Coefficients: elementary symmetric functions of C_k = e^{-a_k}.
#define A1 1.1280610230094226f
#define A2 0.3753279228541867f
#define A3 0.0366994760193147f
#define A4 0.0005530843701478f
#define B1 3.3841830690282678f   // 3*A1
#define B2 0.7506558457083734f   // 2*A2
#define B3 0.0366994760193147f   // A3

__global__ __launch_bounds__(TPB) void lddt_pairs(
    const float* __restrict__ pred, const float* __restrict__ truec,
    const int* __restrict__ isdna, const int* __restrict__ isrna,
    float2* __restrict__ part, int N, int C, int T)
{
  const int wv   = threadIdx.x >> 6;   // which wave (0/1) -> which tile
  const int lane = threadIdx.x & 63;
  const int t = blockIdx.x * 2 + wv;   // linear upper-triangle tile id
  const int b = blockIdx.y;

  // tile id -> (ic, jc), jc >= ic (wave-uniform scalar math)
  const float fC = (float)C;
  int ic = (int)((2.0f*fC + 1.0f -
                  sqrtf((2.0f*fC + 1.0f)*(2.0f*fC + 1.0f) - 8.0f*(float)t)) * 0.5f);
  if (ic > C - 1) ic = C - 1;
  if (ic < 0) ic = 0;
  while (ic > 0 && t < ic*C - ((ic*(ic-1)) >> 1)) --ic;
  while (t >= (ic+1)*C - (((ic+1)*ic) >> 1)) ++ic;
  const int jc = ic + t - (ic*C - ((ic*(ic-1)) >> 1));
  const bool diag = (ic == jc);

  const float C30SQ = (30.0f*L2E)*(30.0f*L2E);
  const float C15SQ = (15.0f*L2E)*(15.0f*L2E);

  __shared__ float4 sp[2][64];  // per-wave slice: scaled pred xyz ; w = j's cutoff^2
  __shared__ float4 st[2][64];  // per-wave slice: scaled true xyz

  {
    const int j = jc * 64 + lane;
    const size_t base = (size_t)b * N + j;
    const float* pp = pred  + base * 3;
    const float* tt = truec + base * 3;
    const float cutj2 = ((isdna[base] | isrna[base]) != 0) ? C30SQ : C15SQ;
    sp[wv][lane] = make_float4(pp[0]*L2E, pp[1]*L2E, pp[2]*L2E, cutj2);
    st[wv][lane] = make_float4(tt[0]*L2E, tt[1]*L2E, tt[2]*L2E, 0.0f);
  }

  const int i = ic * 64 + lane;
  const size_t ibase = (size_t)b * N + i;
  const float pix = pred[ibase*3+0]*L2E, piy = pred[ibase*3+1]*L2E, piz = pred[ibase*3+2]*L2E;
  const float tix = truec[ibase*3+0]*L2E, tiy = truec[ibase*3+1]*L2E, tiz = truec[ibase*3+2]*L2E;
  const bool nuci = ((isdna[ibase] | isrna[ibase]) != 0);

  __syncthreads();   // cheap with 2 waves; guarantees LDS visibility

  float sum = 0.0f;
  int   cnt = 0;

  if (!diag) {
#pragma unroll 8
    for (int jj = 0; jj < 64; ++jj) {
      const float4 P  = sp[wv][jj];
      const float4 T4 = st[wv][jj];
      float dx = P.x - pix, dy = P.y - piy, dz = P.z - piz;
      float dp = __builtin_amdgcn_sqrtf(fmaf(dx, dx, fmaf(dy, dy, dz * dz)));
      float ex = T4.x - tix, ey = T4.y - tiy, ez = T4.z - tiz;
      float d2t = fmaf(ex, ex, fmaf(ey, ey, ez * ez));
      float dt  = __builtin_amdgcn_sqrtf(d2t);

      float e = __builtin_amdgcn_exp2f(fabsf(dt - dp));
      float den = fmaf(fmaf(fmaf(fmaf(A4, e, A3), e, A2), e, A1), e, 1.0f);
      float num = fmaf(fmaf(fmaf(B3, e, B2), e, B1), e, 4.0f);
      float eps4 = num * __builtin_amdgcn_rcpf(den);

      float cut2 = nuci ? P.w : C15SQ;
      bool inc = (d2t < cut2);
      cnt += (int)__popcll(__ballot(inc));
      sum += inc ? eps4 : 0.0f;
    }
  } else {
#pragma unroll 8
    for (int jj = 0; jj < 64; ++jj) {
      const float4 P  = sp[wv][jj];
      const float4 T4 = st[wv][jj];
      float dx = P.x - pix, dy = P.y - piy, dz = P.z - piz;
      float dp = __builtin_amdgcn_sqrtf(fmaf(dx, dx, fmaf(dy, dy, dz * dz)));
      float ex = T4.x - tix, ey = T4.y - tiy, ez = T4.z - tiz;
      float d2t = fmaf(ex, ex, fmaf(ey, ey, ez * ez));
      float dt  = __builtin_amdgcn_sqrtf(d2t);

      float e = __builtin_amdgcn_exp2f(fabsf(dt - dp));
      float den = fmaf(fmaf(fmaf(fmaf(A4, e, A3), e, A2), e, A1), e, 1.0f);
      float num = fmaf(fmaf(fmaf(B3, e, B2), e, B1), e, 4.0f);
      float eps4 = num * __builtin_amdgcn_rcpf(den);

      float cut2 = nuci ? P.w : C15SQ;
      bool inc = (d2t < cut2) && (jj != lane);
      cnt += (int)__popcll(__ballot(inc));
      sum += inc ? eps4 : 0.0f;
    }
  }

  // wave64 butterfly reduce on sum (cnt already wave-uniform via ballot)
  for (int off = 32; off > 0; off >>= 1)
    sum += __shfl_down(sum, off, 64);

  if (lane == 0) {
    const float w = diag ? 1.0f : 2.0f;
    part[(size_t)b * T + t] = make_float2(0.25f * w * sum, w * (float)cnt);
  }
}

__global__ __launch_bounds__(1024) void lddt_final(
    const float2* __restrict__ part, float* __restrict__ out, int B, int T)
{
  __shared__ float rs[16], rc[16];
  float acc = 0.0f;
  for (int b = 0; b < B; ++b) {
    float s = 0.0f, c = 0.0f;
    for (int k = threadIdx.x; k < T; k += 1024) {
      const float2 p = part[(size_t)b * T + k];
      s += p.x;
      c += p.y;
    }
    for (int off = 32; off > 0; off >>= 1) {
      s += __shfl_down(s, off, 64);
      c += __shfl_down(c, off, 64);
    }
    const int wave = threadIdx.x >> 6, lane = threadIdx.x & 63;
    if (lane == 0) { rs[wave] = s; rc[wave] = c; }
    __syncthreads();
    if (threadIdx.x == 0) {
      float S = 0.0f, Cc = 0.0f;
      for (int w = 0; w < 16; ++w) { S += rs[w]; Cc += rc[w]; }
      acc += S / fmaxf(Cc, 1.0f);
    }
    __syncthreads();
  }
  if (threadIdx.x == 0) out[0] = 1.0f - acc / (float)B;
}

extern "C" void kernel_launch(void* const* d_in, const int* in_sizes, int n_in,
                              void* d_out, int out_size, void* d_ws, size_t ws_size,
                              hipStream_t stream)
{
  const float* pred  = (const float*)d_in[0];
  const float* truec = (const float*)d_in[1];
  const int*   isdna = (const int*)d_in[2];
  const int*   isrna = (const int*)d_in[3];
  float* out = (float*)d_out;
  float2* part = (float2*)d_ws;

  const int B = 2;
  const int N = in_sizes[2] / B;       // 4096
  const int C = N / 64;                // 64 chunks
  const int T = C * (C + 1) / 2;       // 2080 triangle tiles (even)

  dim3 grid(T / 2, B);                 // 2 tiles per block (one per wave)
  lddt_pairs<<<grid, TPB, 0, stream>>>(pred, truec, isdna, isrna, part, N, C, T);
  lddt_final<<<1, 1024, 0, stream>>>(part, out, B, T);
}